// Round 6
// baseline (277.302 us; speedup 1.0000x reference)
//
#include <hip/hip_runtime.h>

// ContrastLoss: loss = -sum_i dot(f_s[i], f_t[i]) / B   (B=65536, D=512, fp32)
// Streaming reduction over 2 x 128 MiB fp32. Round-5 result: 100 us on the
// main kernel (2.7 TB/s effective) with VGPR_Count=16 -> compiler serialized
// loads, ~2 in flight per wave. Fix: explicit 8-load batches (4x float4 per
// input) into named arrays so 8 independent loads issue back-to-back per
// iteration, while staying <=64 VGPR (full 8 waves/SIMD occupancy).
// Each block owns a contiguous chunk (n4/NBLK float4s) for DRAM locality.

#define NBLK 2048
#define NTHR 256
#define BATCH 4   // float4 per input per batch -> 8 loads / 32 data VGPRs in flight

__global__ __launch_bounds__(NTHR) void
contrast_partial(const float4* __restrict__ a, const float4* __restrict__ b,
                 float* __restrict__ partials, long n4) {
    const int  tid   = threadIdx.x;
    const long chunk = (n4 + NBLK - 1) / NBLK;          // per-block float4 count
    const long base  = (long)blockIdx.x * chunk;
    const long end   = (base + chunk < n4) ? (base + chunk) : n4;

    float acc = 0.0f;

    long off = base;
    // fast path: full batches of BATCH*NTHR float4s
    for (; off + BATCH * NTHR <= end; off += BATCH * NTHR) {
        float4 x[BATCH], y[BATCH];
        #pragma unroll
        for (int j = 0; j < BATCH; ++j) x[j] = a[off + j * NTHR + tid];
        #pragma unroll
        for (int j = 0; j < BATCH; ++j) y[j] = b[off + j * NTHR + tid];
        #pragma unroll
        for (int j = 0; j < BATCH; ++j) {
            acc = fmaf(x[j].x, y[j].x, acc);
            acc = fmaf(x[j].y, y[j].y, acc);
            acc = fmaf(x[j].z, y[j].z, acc);
            acc = fmaf(x[j].w, y[j].w, acc);
        }
    }
    // tail (not taken for the fixed 65536x512 shape: 4096 % 1024 == 0)
    for (long i = off + tid; i < end; i += NTHR) {
        float4 x = a[i];
        float4 y = b[i];
        acc = fmaf(x.x, y.x, acc);
        acc = fmaf(x.y, y.y, acc);
        acc = fmaf(x.z, y.z, acc);
        acc = fmaf(x.w, y.w, acc);
    }

    // wave-64 butterfly reduce
    #pragma unroll
    for (int o = 32; o > 0; o >>= 1)
        acc += __shfl_down(acc, o, 64);

    __shared__ float smem[NTHR / 64];
    int lane = tid & 63;
    int wave = tid >> 6;
    if (lane == 0) smem[wave] = acc;
    __syncthreads();

    if (tid == 0) {
        float s = 0.0f;
        #pragma unroll
        for (int w = 0; w < NTHR / 64; ++w) s += smem[w];
        partials[blockIdx.x] = s;
    }
}

__global__ __launch_bounds__(NTHR) void
contrast_finalize(const float* __restrict__ partials, float* __restrict__ out,
                  int np, float neg_inv_b) {
    float acc = 0.0f;
    for (int i = threadIdx.x; i < np; i += blockDim.x)
        acc += partials[i];

    #pragma unroll
    for (int o = 32; o > 0; o >>= 1)
        acc += __shfl_down(acc, o, 64);

    __shared__ float smem[NTHR / 64];
    int lane = threadIdx.x & 63;
    int wave = threadIdx.x >> 6;
    if (lane == 0) smem[wave] = acc;
    __syncthreads();

    if (threadIdx.x == 0) {
        float s = 0.0f;
        #pragma unroll
        for (int w = 0; w < NTHR / 64; ++w) s += smem[w];
        out[0] = s * neg_inv_b;   // -sum / B
    }
}

extern "C" void kernel_launch(void* const* d_in, const int* in_sizes, int n_in,
                              void* d_out, int out_size, void* d_ws, size_t ws_size,
                              hipStream_t stream) {
    const float4* f_s = (const float4*)d_in[0];
    const float4* f_t = (const float4*)d_in[1];
    float* out = (float*)d_out;
    float* partials = (float*)d_ws;   // NBLK floats of scratch

    const long n  = (long)in_sizes[0];        // B*D = 33,554,432
    const long n4 = n / 4;                    // float4 count
    const long B  = n / 512;                  // D=512 per reference
    const float neg_inv_b = -1.0f / (float)B;

    contrast_partial<<<NBLK, NTHR, 0, stream>>>(f_s, f_t, partials, n4);
    contrast_finalize<<<1, NTHR, 0, stream>>>(partials, out, NBLK, neg_inv_b);
}